// Round 1
// 673.704 us; speedup vs baseline: 1.0516x; 1.0516x over previous
//
#include <hip/hip_runtime.h>
#include <hip/hip_bf16.h>

typedef __hip_bfloat16 bf16;
typedef __attribute__((ext_vector_type(8))) short short8;
typedef __attribute__((ext_vector_type(4))) float f32x4;

#define NN 2048
#define EE 4096
#define LL 49
#define LRR 16
#define NYY 3
#define CC 128
#define HH 128

#define K1P 2432   // 2401 padded to x64 (P1 / BT1 K)
#define K2P 2496   // 2450 padded to x64 (P2 / BT2 K)

__device__ __forceinline__ float siluf(float v) { return v * (1.0f / (1.0f + __expf(-v))); }
__device__ __forceinline__ bf16 f2b(float v) { return __float2bfloat16(v); }

// ---------------- weight convert + transpose: out[n*Kp+k] = bf16(in[k*N+n]), zero-pad k>=K ----------------
struct TJob { const float* in; bf16* out; int K, N, Kp; };
struct TJobs { TJob j[6]; };

__global__ __launch_bounds__(256) void transpose_cvt_kernel(TJobs jobs) {
  TJob jb = jobs.j[blockIdx.y];
  int i = blockIdx.x * 256 + threadIdx.x;
  if (i < jb.N * jb.Kp) {
    int n = i / jb.Kp, k = i - n * jb.Kp;
    jb.out[i] = (k < jb.K) ? f2b(jb.in[(long)k * jb.N + n]) : f2b(0.f);
  }
}

// ---------------- CG weight prep: BT1[32][K1P], BT2[64][K2P] (transposed, bf16, zero-padded) ----------------
__global__ __launch_bounds__(256) void cg_prep_kernel(
    const float* __restrict__ Wcg1, const float* __restrict__ Wcg21,
    const float* __restrict__ Wcg22, bf16* __restrict__ BT1, bf16* __restrict__ BT2) {
  int i = blockIdx.x * 256 + threadIdx.x;
  if (blockIdx.y == 0) {
    if (i < 32 * K1P) {
      int o = i / K1P, k = i - o * K1P;
      float v = (o < 25 && k < 2401) ? Wcg1[k * 25 + o] : 0.f;
      BT1[i] = f2b(v);
    }
  } else {
    if (i < 64 * K2P) {
      int o = i / K2P, k = i - o * K2P;
      float v = 0.f;
      if (o < 49) {
        if (k < 1225) v = Wcg21[k * 49 + o];
        else if (k < 2450) v = Wcg22[(k - 1225) * 49 + o];
      }
      BT2[i] = f2b(v);
    }
  }
}

// ---------------- per-node channel mean ----------------
__global__ __launch_bounds__(256) void node_mean_kernel(const float* __restrict__ x,
                                                        float* __restrict__ xmean) {
  int row = blockIdx.x * 4 + (threadIdx.x >> 6);
  int lane = threadIdx.x & 63;
  const float* p = x + (long)row * CC;
  float s = p[lane] + p[lane + 64];
  for (int off = 32; off > 0; off >>= 1) s += __shfl_down(s, off);
  if (lane == 0) xmean[row] = s * (1.0f / 128.0f);
}

// ---------------- P1[e][k] = xm_i * ym_j (k = i*49+j), bf16, zero-pad ----------------
__global__ __launch_bounds__(256) void build_p1_kernel(
    const float* __restrict__ xmean, const int* __restrict__ eidx, bf16* __restrict__ P1) {
  __shared__ float sxm[49], sym[49];
  int e = blockIdx.x, tid = threadIdx.x;
  int s = eidx[e], d = eidx[EE + e];
  if (tid < 49) { sxm[tid] = xmean[s * 49 + tid]; sym[tid] = xmean[d * 49 + tid]; }
  __syncthreads();
  for (int idx = tid; idx < K1P; idx += 256) {
    float v = 0.f;
    if (idx < 2401) { int i = idx / 49, j = idx - i * 49; v = sxm[i] * sym[j]; }
    P1[(long)e * K1P + idx] = f2b(v);
  }
}

// ---------------- P2[e][k]: k<1225: xm_i*mid_m; k<2450: ym_i*mid_m; pad 0 ----------------
__global__ __launch_bounds__(256) void build_p2_kernel(
    const float* __restrict__ xmean, const float* __restrict__ mid,
    const int* __restrict__ eidx, bf16* __restrict__ P2) {
  __shared__ float sxm[49], sym[49], smid[25];
  int e = blockIdx.x, tid = threadIdx.x;
  int s = eidx[e], d = eidx[EE + e];
  if (tid < 49) { sxm[tid] = xmean[s * 49 + tid]; sym[tid] = xmean[d * 49 + tid]; }
  if (tid >= 64 && tid < 89) smid[tid - 64] = mid[e * 32 + tid - 64];
  __syncthreads();
  for (int idx = tid; idx < K2P; idx += 256) {
    float v = 0.f;
    if (idx < 1225) { int i = idx / 25, m = idx - i * 25; v = sxm[i] * smid[m]; }
    else if (idx < 2450) { int kk = idx - 1225; int i = kk / 25, m = kk - i * 25; v = sym[i] * smid[m]; }
    P2[(long)e * K2P + idx] = f2b(v);
  }
}

// ---------------- small-N MFMA GEMM: C[M][NI*16] = A[M][K]bf16 @ BT[NI*16][K]^T ----------------
template <int NI>
__global__ __launch_bounds__(256) void gemm_smalln(
    const bf16* __restrict__ A, const bf16* __restrict__ BT,
    float* __restrict__ C, int K) {
  __shared__ short As[64 * 64];
  __shared__ short Bs[NI * 16 * 64];
  const int tid = threadIdx.x, w = tid >> 6, lane = tid & 63;
  const int lm = lane & 15, q = lane >> 4;
  const int bm = blockIdx.x * 64;
  f32x4 acc[NI];
#pragma unroll
  for (int ni = 0; ni < NI; ++ni) acc[ni] = (f32x4){0.f, 0.f, 0.f, 0.f};
  for (int k0 = 0; k0 < K; k0 += 64) {
    __syncthreads();
#pragma unroll
    for (int it = 0; it < 2; ++it) {
      int lc = it * 256 + tid;
      int m = lc >> 3, k8 = lc & 7;
      uint4 v = *(const uint4*)((const char*)A + ((long)(bm + m) * K + k0 + k8 * 8) * 2);
      *(uint4*)&As[(m * 8 + (k8 ^ (m & 7))) * 8] = v;
    }
#pragma unroll
    for (int it = 0; it < NI / 2; ++it) {
      int lc = it * 256 + tid;
      int n = lc >> 3, k8 = lc & 7;
      uint4 v = *(const uint4*)((const char*)BT + ((long)n * K + k0 + k8 * 8) * 2);
      *(uint4*)&Bs[(n * 8 + (k8 ^ (n & 7))) * 8] = v;
    }
    __syncthreads();
#pragma unroll
    for (int ks = 0; ks < 2; ++ks) {
      short8 af = *(const short8*)&As[(w * 16 + lm) * 64 + ((ks * 4 + q) ^ (lm & 7)) * 8];
#pragma unroll
      for (int ni = 0; ni < NI; ++ni) {
        short8 bfr = *(const short8*)&Bs[(ni * 16 + lm) * 64 + ((ks * 4 + q) ^ (lm & 7)) * 8];
        acc[ni] = __builtin_amdgcn_mfma_f32_16x16x32_bf16(af, bfr, acc[ni], 0, 0, 0);
      }
    }
  }
#pragma unroll
  for (int ni = 0; ni < NI; ++ni) {
    int col = ni * 16 + lm;
#pragma unroll
    for (int r = 0; r < 4; ++r) {
      int row = bm + w * 16 + q * 4 + r;
      C[(long)row * (NI * 16) + col] = acc[ni][r];
    }
  }
}

// ---------------- feat build -> bf16 [8192][2112] (rows e, 4096+e), pad cols 2064..2111 = 0 ----------------
__global__ __launch_bounds__(256) void build_feat_kernel(
    const float* __restrict__ x, const float* __restrict__ x_glovec,
    const float* __restrict__ wig_node, const int* __restrict__ eidx,
    bf16* __restrict__ featst) {
  __shared__ float wig[256];
  __shared__ float xa[2048], xb[2048], tmp[2048];
  int e = blockIdx.x, tid = threadIdx.x;
  int s = eidx[e], d = eidx[EE + e];
  wig[tid] = wig_node[e * 256 + tid];
  if (tid < 48) {
    featst[(long)e * 2112 + 2064 + tid] = f2b(0.f);
    featst[(long)(EE + e) * 2112 + 2064 + tid] = f2b(0.f);
  }
  for (int idx = tid; idx < 2048; idx += 256) {
    int l = idx >> 7, c = idx & 127;
    xa[idx] = x[((long)s * LL + l) * CC + c];
    xb[idx] = x[((long)d * LL + l) * CC + c];
  }
  __syncthreads();
  for (int idx = tid; idx < 2048; idx += 256) {
    int i = idx >> 7, c = idx & 127;
    float a = 0.f;
#pragma unroll
    for (int j = 0; j < 16; ++j) a += wig[j * 16 + i] * xa[j * 128 + c];
    tmp[idx] = a;
    featst[(long)e * 2112 + i * 129 + c] = f2b(a);
  }
  __syncthreads();
  if (tid < 16) {
    float m = 0.f;
    for (int c = 0; c < 128; ++c) m += tmp[tid * 128 + c];
    featst[(long)e * 2112 + tid * 129 + 128] = f2b(m * (1.0f / 128.0f) * x_glovec[(long)d * 16 + tid]);
  }
  __syncthreads();
  for (int idx = tid; idx < 2048; idx += 256) {
    int i = idx >> 7, c = idx & 127;
    float a = 0.f;
#pragma unroll
    for (int j = 0; j < 16; ++j) a += wig[j * 16 + i] * xb[j * 128 + c];
    tmp[idx] = a;
    featst[(long)(EE + e) * 2112 + i * 129 + c] = f2b(a);
  }
  __syncthreads();
  if (tid < 16) {
    float m = 0.f;
    for (int c = 0; c < 128; ++c) m += tmp[tid * 128 + c];
    featst[(long)(EE + e) * 2112 + tid * 129 + 128] = f2b(m * (1.0f / 128.0f) * x_glovec[(long)s * 16 + tid]);
  }
}

// ---------------- fp32 tiled GEMM (only for tiny xe GEMM) ----------------
__global__ __launch_bounds__(256) void gemm_f32_silu(
    const float* __restrict__ A, const float* __restrict__ B,
    const float* __restrict__ bias, float* __restrict__ C, int M, int N, int K) {
  __shared__ float As[16][68];
  __shared__ float Bs[16][64];
  const int tid = threadIdx.x;
  const int bm = blockIdx.x * 64, bn = blockIdx.y * 64;
  const int tx = tid & 15, ty = tid >> 4;
  const int ar = tid >> 2, ak = (tid & 3) * 4;
  const int br = tid >> 4, bc = (tid & 15) * 4;
  float acc[4][4] = {};
  const float* Ap = A + (long)(bm + ar) * K + ak;
  const float* Bp = B + (long)br * N + bn + bc;
  for (int k0 = 0; k0 < K; k0 += 16) {
    const float4 av = *(const float4*)(Ap + k0);
    const float4 bv = *(const float4*)(Bp + (long)k0 * N);
    __syncthreads();
    As[ak + 0][ar] = av.x; As[ak + 1][ar] = av.y;
    As[ak + 2][ar] = av.z; As[ak + 3][ar] = av.w;
    *(float4*)&Bs[br][bc] = bv;
    __syncthreads();
#pragma unroll
    for (int k = 0; k < 16; ++k) {
      const float4 a = *(const float4*)&As[k][ty * 4];
      const float4 b = *(const float4*)&Bs[k][tx * 4];
      acc[0][0] += a.x * b.x; acc[0][1] += a.x * b.y; acc[0][2] += a.x * b.z; acc[0][3] += a.x * b.w;
      acc[1][0] += a.y * b.x; acc[1][1] += a.y * b.y; acc[1][2] += a.y * b.z; acc[1][3] += a.y * b.w;
      acc[2][0] += a.z * b.x; acc[2][1] += a.z * b.y; acc[2][2] += a.z * b.z; acc[2][3] += a.z * b.w;
      acc[3][0] += a.w * b.x; acc[3][1] += a.w * b.y; acc[3][2] += a.w * b.z; acc[3][3] += a.w * b.w;
    }
  }
#pragma unroll
  for (int i = 0; i < 4; ++i) {
    int row = bm + ty * 4 + i;
#pragma unroll
    for (int j = 0; j < 4; ++j) {
      int col = bn + tx * 4 + j;
      C[(long)row * N + col] = siluf(acc[i][j] + bias[col]);
    }
  }
}

// ---------------- bf16 MFMA GEMM: C = epi(A[MxK]bf16 @ BT[NxK]bf16^T + bias) ----------------
template <int BM, bool SILU, bool XE, bool OUT_BF16>
__global__ __launch_bounds__(256) void gemm_mfma(
    const bf16* __restrict__ A, const bf16* __restrict__ B0, const bf16* __restrict__ B1,
    const float* __restrict__ bias0, const float* __restrict__ bias1,
    const float* __restrict__ xe, void* __restrict__ Cout,
    int M, int N, int K, int half) {
  constexpr int MI = BM / 32;
  __shared__ short As[BM * 64];
  __shared__ short Bs[128 * 64];
  const int tid = threadIdx.x;
  const int w = tid >> 6, lane = tid & 63;
  const int lm = lane & 15, q = lane >> 4;
  const int bm = blockIdx.x * BM, bn = blockIdx.y * 128;
  const int wm = (w & 1) * (BM / 2), wn = (w >> 1) * 64;
  const bf16* Bp = (bm < half) ? B0 : B1;
  const float* bias = (bm < half) ? bias0 : bias1;

  f32x4 acc[MI][4];
#pragma unroll
  for (int mi = 0; mi < MI; ++mi)
#pragma unroll
    for (int ni = 0; ni < 4; ++ni) acc[mi][ni] = (f32x4){0.f, 0.f, 0.f, 0.f};

  for (int k0 = 0; k0 < K; k0 += 64) {
    __syncthreads();
#pragma unroll
    for (int it = 0; it < BM / 32; ++it) {
      int lc = it * 256 + tid;
      int m = lc >> 3, k8 = lc & 7;
      uint4 v = *(const uint4*)((const char*)A + ((long)(bm + m) * K + k0 + k8 * 8) * 2);
      *(uint4*)&As[(m * 8 + (k8 ^ (m & 7))) * 8] = v;
    }
#pragma unroll
    for (int it = 0; it < 4; ++it) {
      int lc = it * 256 + tid;
      int n = lc >> 3, k8 = lc & 7;
      uint4 v = *(const uint4*)((const char*)Bp + ((long)(bn + n) * K + k0 + k8 * 8) * 2);
      *(uint4*)&Bs[(n * 8 + (k8 ^ (n & 7))) * 8] = v;
    }
    __syncthreads();
#pragma unroll
    for (int ks = 0; ks < 2; ++ks) {
      short8 af[MI], bfr[4];
#pragma unroll
      for (int mi = 0; mi < MI; ++mi) {
        int row = wm + mi * 16 + lm;
        af[mi] = *(const short8*)&As[row * 64 + ((ks * 4 + q) ^ (lm & 7)) * 8];
      }
#pragma unroll
      for (int ni = 0; ni < 4; ++ni) {
        int row = wn + ni * 16 + lm;
        bfr[ni] = *(const short8*)&Bs[row * 64 + ((ks * 4 + q) ^ (lm & 7)) * 8];
      }
#pragma unroll
      for (int mi = 0; mi < MI; ++mi)
#pragma unroll
        for (int ni = 0; ni < 4; ++ni)
          acc[mi][ni] = __builtin_amdgcn_mfma_f32_16x16x32_bf16(af[mi], bfr[ni], acc[mi][ni], 0, 0, 0);
    }
  }
#pragma unroll
  for (int mi = 0; mi < MI; ++mi) {
#pragma unroll
    for (int ni = 0; ni < 4; ++ni) {
      int col = bn + wn + ni * 16 + lm;
      float bcol = bias[col];
#pragma unroll
      for (int r = 0; r < 4; ++r) {
        int row = bm + wm + mi * 16 + q * 4 + r;
        float v = acc[mi][ni][r] + bcol;
        if (SILU) v = siluf(v);
        if (XE) v *= xe[(row / 3) * HH + col];
        if (OUT_BF16) ((bf16*)Cout)[(long)row * N + col] = f2b(v);
        else ((float*)Cout)[(long)row * N + col] = v;
      }
    }
  }
}

// ---------------- sh = wig_node @ (o1 + o2) ----------------
__global__ __launch_bounds__(256) void rotback_kernel(
    const float* __restrict__ wig_node, const float* __restrict__ o1,
    const float* __restrict__ o2, float* __restrict__ sh) {
  __shared__ float wig[256];
  __shared__ float osum[2048];
  int e = blockIdx.x, tid = threadIdx.x;
  wig[tid] = wig_node[e * 256 + tid];
  for (int idx = tid; idx < 2048; idx += 256)
    osum[idx] = o1[(long)e * 2048 + idx] + o2[(long)e * 2048 + idx];
  __syncthreads();
  for (int idx = tid; idx < 2048; idx += 256) {
    int i = idx >> 7, c = idx & 127;
    float a = 0.f;
#pragma unroll
    for (int j = 0; j < 16; ++j) a += wig[i * 16 + j] * osum[j * 128 + c];
    sh[(long)e * 2048 + idx] = a;
  }
}

// ---------------- msg(bf16) = wigner @ z via per-edge MFMA, split-bf16 (hi/lo) for fp32-equivalent accuracy ----
// z = 2(xs+xt) + asum + pad(sh): [49][128] per edge. A = wigner [48 rows (n*16+r)][49->64].
// Two N-chunks of 64 cols. fp32 z staged at stride 65 (odd -> conflict-free column reads in transpose).
__global__ __launch_bounds__(256) void rotate_msg_kernel(
    const float* __restrict__ x, const float* __restrict__ wigner,
    const int* __restrict__ eidx, const float* __restrict__ asum,
    const float* __restrict__ sh, bf16* __restrict__ msg) {
  __shared__ float z[49 * 65];
  __shared__ bf16 zTh[64 * 64], zTl[64 * 64];
  __shared__ bf16 Ah[48 * 64], Al[48 * 64];
  __shared__ float as_s[49];
  const int e = blockIdx.x, tid = threadIdx.x;
  const int s = eidx[e], d = eidx[EE + e];
  const int w = tid >> 6, lane = tid & 63;
  const int lm = lane & 15, q = lane >> 4;

  if (tid < 49) as_s[tid] = asum[e * 64 + tid];
  // zero-pad A for k in [49,64)  (disjoint from fill loop -> no barrier needed between them)
  for (int i = tid; i < 48 * 15; i += 256) {
    int m = i / 15, k = 49 + (i - m * 15);
    int off = m * 64 + (((k >> 3) ^ (m & 7)) << 3) + (k & 7);
    Ah[off] = f2b(0.f); Al[off] = f2b(0.f);
  }
  // stage wigner -> A hi/lo (XOR-swizzled rows, coalesced global reads)
  for (int i = tid; i < 2352; i += 256) {
    int m = i / 49, k = i - m * 49;
    float v = wigner[(long)e * 2352 + i];
    bf16 h = f2b(v);
    bf16 l = f2b(v - __bfloat162float(h));
    int off = m * 64 + (((k >> 3) ^ (m & 7)) << 3) + (k & 7);
    Ah[off] = h; Al[off] = l;
  }
  __syncthreads();

  // hoist A fragments into registers (reused by both chunks)
  short8 ah[3][2], al[3][2];
#pragma unroll
  for (int mi = 0; mi < 3; ++mi)
#pragma unroll
    for (int ks = 0; ks < 2; ++ks) {
      int off = (mi * 16 + lm) * 64 + (((ks * 4 + q) ^ (lm & 7)) << 3);
      ah[mi][ks] = *(const short8*)&Ah[off];
      al[mi][ks] = *(const short8*)&Al[off];
    }

#pragma unroll
  for (int ch = 0; ch < 2; ++ch) {
    const int c0 = ch * 64;
    // build z fp32 chunk [49][65-pad] (coalesced gather; 256B contiguous per row-chunk)
    for (int idx = tid; idx < 49 * 64; idx += 256) {
      int l = idx >> 6, cc = idx & 63;
      float v = 2.0f * (x[((long)s * LL + l) * CC + c0 + cc] +
                        x[((long)d * LL + l) * CC + c0 + cc]) + as_s[l];
      if (l < 16) v += sh[(long)e * 2048 + l * 128 + c0 + cc];
      z[l * 65 + cc] = v;
    }
    __syncthreads();
    // transpose + hi/lo split: zT[c][b], swizzled like the GEMM B layout.
    // reads: lanes vary b at fixed c -> banks (b*65+c)%32 = (b+c)%32, conflict-free.
    // writes: one row per wave per iter, 128B contiguous-permuted, conflict-free.
    {
      int b = tid & 63, cb = tid >> 6;
#pragma unroll
      for (int i = 0; i < 16; ++i) {
        int c = cb + i * 4;
        float v = (b < 49) ? z[b * 65 + c] : 0.f;
        bf16 h = f2b(v);
        bf16 l = f2b(v - __bfloat162float(h));
        int off = c * 64 + (((b >> 3) ^ (c & 7)) << 3) + (b & 7);
        zTh[off] = h; zTl[off] = l;
      }
    }
    __syncthreads();
    // MFMA: wave w -> n-tile w (cols c0 + w*16 + lm), m-tiles 0..2 (= NY index)
    short8 bh[2], bl[2];
#pragma unroll
    for (int ks = 0; ks < 2; ++ks) {
      int off = (w * 16 + lm) * 64 + (((ks * 4 + q) ^ (lm & 7)) << 3);
      bh[ks] = *(const short8*)&zTh[off];
      bl[ks] = *(const short8*)&zTl[off];
    }
    f32x4 acc[3];
#pragma unroll
    for (int mi = 0; mi < 3; ++mi) acc[mi] = (f32x4){0.f, 0.f, 0.f, 0.f};
#pragma unroll
    for (int mi = 0; mi < 3; ++mi)
#pragma unroll
      for (int ks = 0; ks < 2; ++ks) {
        acc[mi] = __builtin_amdgcn_mfma_f32_16x16x32_bf16(ah[mi][ks], bh[ks], acc[mi], 0, 0, 0);
        acc[mi] = __builtin_amdgcn_mfma_f32_16x16x32_bf16(ah[mi][ks], bl[ks], acc[mi], 0, 0, 0);
        acc[mi] = __builtin_amdgcn_mfma_f32_16x16x32_bf16(al[mi][ks], bh[ks], acc[mi], 0, 0, 0);
      }
    // epilogue: D row = q*4+r (reduced-basis row), col = lm; m-tile index == NY tap
    {
      int c = c0 + w * 16 + lm;
#pragma unroll
      for (int mi = 0; mi < 3; ++mi) {
        long base = ((long)e * 3 + mi) * 2048 + c;
#pragma unroll
        for (int r = 0; r < 4; ++r)
          msg[base + (q * 4 + r) * 128] = f2b(acc[mi][r]);
      }
    }
    // no barrier needed here: next chunk's z-build touches only z[], which all
    // waves finished reading (transpose) before the pre-MFMA barrier.
  }
}

// ---------------- out = INV_SQRT_3 * wigner_inv @ mean_ny(m2) ----------------
__global__ __launch_bounds__(256) void out_kernel(
    const float* __restrict__ m2, const float* __restrict__ wigner_inv,
    float* __restrict__ out) {
  __shared__ float mr[2048];
  __shared__ float wv[784];
  int e = blockIdx.x, tid = threadIdx.x;
  for (int idx = tid; idx < 2048; idx += 256)
    mr[idx] = (m2[((long)e * 3 + 0) * 2048 + idx] + m2[((long)e * 3 + 1) * 2048 + idx] +
               m2[((long)e * 3 + 2) * 2048 + idx]) * (1.0f / 3.0f);
  for (int idx = tid; idx < 784; idx += 256) wv[idx] = wigner_inv[(long)e * 784 + idx];
  __syncthreads();
  for (int idx = tid; idx < 6272; idx += 256) {
    int bq = idx >> 7, c = idx & 127;
    const float* wp = wv + bq * 16;
    float a = 0.f;
#pragma unroll
    for (int r = 0; r < 16; ++r) a += wp[r] * mr[r * 128 + c];
    out[(long)e * 6272 + idx] = a * 0.57735026918962576f;
  }
}

// ---------------- host side ----------------
extern "C" void kernel_launch(void* const* d_in, const int* in_sizes, int n_in,
                              void* d_out, int out_size, void* d_ws, size_t ws_size,
                              hipStream_t stream) {
  (void)in_sizes; (void)n_in; (void)out_size; (void)ws_size;
  const float* x        = (const float*)d_in[0];
  const float* x_glovec = (const float*)d_in[2];
  const float* x_edge   = (const float*)d_in[3];
  const int*   eidx     = (const int*)d_in[4];
  const float* W_cg1   = (const float*)d_in[8];
  const float* W_cg21  = (const float*)d_in[9];
  const float* W_cg22  = (const float*)d_in[10];
  const float* Wn1a = (const float*)d_in[11];
  const float* bn1a = (const float*)d_in[12];
  const float* Wn1b = (const float*)d_in[13];
  const float* bn1b = (const float*)d_in[14];
  const float* Wn2a = (const float*)d_in[15];
  const float* bn2a = (const float*)d_in[16];
  const float* Wn2b = (const float*)d_in[17];
  const float* bn2b = (const float*)d_in[18];
  const float* Wd   = (const float*)d_in[19];
  const float* bd   = (const float*)d_in[20];
  const float* Wp1  = (const float*)d_in[21];
  const float* bp1  = (const float*)d_in[22];
  const float* Wp2  = (const float*)d_in[23];
  const float* bp2  = (const float*)d_in[24];
  const float* wigner     = (const float*)d_in[25];
  const float* wigner_inv = (const float*)d_in[26];
  const float* wig_node   = (const float*)d_in[27];

  char* W = (char*)d_ws;
  bf16*  featst = (bf16*)(W + 0);            // 8192 x 2112 bf16 (34.6 MB)
  float* ostack = (float*)(W + 34603008);    // 8192 x 2048 f32  (67 MB)
  float* m2     = (float*)(W + 0);           // alias: 12288 x 2048 f32 (100.7 MB)
  float* p_sh   = (float*)(W + 101711872);   // 4096 x 2048 f32
  bf16*  msg    = (bf16*)(W + 135266304);    // 12288 x 2048 bf16 (50.3 MB)
  bf16*  P1     = (bf16*)(W + 135266304);    // alias in msg region: 4096 x 2432 bf16 (19.9 MB)
  bf16*  P2     = (bf16*)(W + 155189248);    // alias in msg region: 4096 x 2496 bf16 (20.4 MB)
  bf16*  hstack = (bf16*)(W + 185597952);    // 8192 x 128 bf16
  bf16*  m1     = (bf16*)(W + 187695104);    // 12288 x 128 bf16
  float* p_xe   = (float*)(W + 190840832);   // 4096 x 128 f32
  float* p_xmean= (float*)(W + 192937984);   // 100352 f32
  bf16*  BTa    = (bf16*)(W + 194142208);    // 2 x 128 x 2112
  bf16*  BTb    = (bf16*)(W + 195223552);    // 2 x 2048 x 128
  bf16*  BTp1   = (bf16*)(W + 196272128);    // 128 x 2048
  bf16*  BTp2   = (bf16*)(W + 196796416);    // 2048 x 128 (ends 197320704)
  float* p_asum = (float*)(W + 197320704);   // 4096 x 64 f32 (1 MB)
  float* p_mid  = (float*)(W + 198369280);   // 4096 x 32 f32 (512 KB)
  bf16*  BT1    = (bf16*)(W + 198893568);    // 32 x 2432 bf16 (152 KB)
  bf16*  BT2    = (bf16*)(W + 199049216);    // 64 x 2496 bf16 (312 KB; ends 199368704)

  TJobs tj;
  tj.j[0] = {Wn1a, BTa,            2064, 128, 2112};
  tj.j[1] = {Wn2a, BTa + 270336,   2064, 128, 2112};
  tj.j[2] = {Wn1b, BTb,            128, 2048, 128};
  tj.j[3] = {Wn2b, BTb + 262144,   128, 2048, 128};
  tj.j[4] = {Wp1,  BTp1,           2048, 128, 2048};
  tj.j[5] = {Wp2,  BTp2,           128, 2048, 128};
  transpose_cvt_kernel<<<dim3(1056, 6), 256, 0, stream>>>(tj);
  cg_prep_kernel<<<dim3(624, 2), 256, 0, stream>>>(W_cg1, W_cg21, W_cg22, BT1, BT2);

  node_mean_kernel<<<(NN * LL) / 4, 256, 0, stream>>>(x, p_xmean);
  // CG bilinears as outer-product GEMMs
  build_p1_kernel<<<EE, 256, 0, stream>>>(p_xmean, eidx, P1);
  gemm_smalln<2><<<EE / 64, 256, 0, stream>>>(P1, BT1, p_mid, K1P);
  build_p2_kernel<<<EE, 256, 0, stream>>>(p_xmean, p_mid, eidx, P2);
  gemm_smalln<4><<<EE / 64, 256, 0, stream>>>(P2, BT2, p_asum, K2P);

  gemm_f32_silu<<<dim3(EE / 64, 2), 256, 0, stream>>>(x_edge, Wd, bd, p_xe, EE, HH, 128);
  build_feat_kernel<<<EE, 256, 0, stream>>>(x, x_glovec, wig_node, eidx, featst);
  // h = silu(feat @ Wna): M=8192, N=128, K=2112, stacked weights
  gemm_mfma<64, true, false, true><<<dim3(128, 1), 256, 0, stream>>>(
      featst, BTa, BTa + 270336, bn1a, bn2a, nullptr, hstack, 8192, 128, 2112, 4096);
  // o = silu(h @ Wnb): M=8192, N=2048, K=128, stacked weights, fp32 out
  gemm_mfma<128, true, false, false><<<dim3(64, 16), 256, 0, stream>>>(
      hstack, BTb, BTb + 262144, bn1b, bn2b, nullptr, ostack, 8192, 2048, 128, 4096);
  rotback_kernel<<<EE, 256, 0, stream>>>(wig_node, ostack, ostack + (long)4096 * 2048, p_sh);
  rotate_msg_kernel<<<EE, 256, 0, stream>>>(x, wigner, eidx, p_asum, p_sh, msg);
  // m1 = silu(msg @ Wp1) * xe: M=12288, N=128, K=2048, bf16 out
  gemm_mfma<64, true, true, true><<<dim3(192, 1), 256, 0, stream>>>(
      msg, BTp1, BTp1, bp1, bp1, p_xe, m1, 12288, 128, 2048, 1 << 30);
  // m2 = silu(m1 @ Wp2): M=12288, N=2048, K=128, fp32 out
  gemm_mfma<128, true, false, false><<<dim3(96, 16), 256, 0, stream>>>(
      m1, BTp2, BTp2, bp2, bp2, nullptr, m2, 12288, 2048, 128, 1 << 30);
  out_kernel<<<EE, 256, 0, stream>>>(m2, wigner_inv, (float*)d_out);
}

// Round 2
// 576.537 us; speedup vs baseline: 1.2289x; 1.1685x over previous
//
#include <hip/hip_runtime.h>
#include <hip/hip_bf16.h>

typedef __hip_bfloat16 bf16;
typedef __attribute__((ext_vector_type(8))) short short8;
typedef __attribute__((ext_vector_type(4))) float f32x4;

#define NN 2048
#define EE 4096
#define LL 49
#define LRR 16
#define NYY 3
#define CC 128
#define HH 128

#define K1P 2432   // 2401 padded to x64 (P1 / BT1 K)
#define K2P 2496   // 2450 padded to x64 (P2 / BT2 K)

__device__ __forceinline__ float siluf(float v) { return v * (1.0f / (1.0f + __expf(-v))); }
__device__ __forceinline__ bf16 f2b(float v) { return __float2bfloat16(v); }

// ---------------- weight convert + transpose: out[n*Kp+k] = bf16(in[k*N+n]), zero-pad k>=K ----------------
struct TJob { const float* in; bf16* out; int K, N, Kp; };
struct TJobs { TJob j[6]; };

__global__ __launch_bounds__(256) void transpose_cvt_kernel(TJobs jobs) {
  TJob jb = jobs.j[blockIdx.y];
  int i = blockIdx.x * 256 + threadIdx.x;
  if (i < jb.N * jb.Kp) {
    int n = i / jb.Kp, k = i - n * jb.Kp;
    jb.out[i] = (k < jb.K) ? f2b(jb.in[(long)k * jb.N + n]) : f2b(0.f);
  }
}

// ---------------- CG weight prep: BT1[32][K1P], BT2[64][K2P] (transposed, bf16, zero-padded) ----------------
__global__ __launch_bounds__(256) void cg_prep_kernel(
    const float* __restrict__ Wcg1, const float* __restrict__ Wcg21,
    const float* __restrict__ Wcg22, bf16* __restrict__ BT1, bf16* __restrict__ BT2) {
  int i = blockIdx.x * 256 + threadIdx.x;
  if (blockIdx.y == 0) {
    if (i < 32 * K1P) {
      int o = i / K1P, k = i - o * K1P;
      float v = (o < 25 && k < 2401) ? Wcg1[k * 25 + o] : 0.f;
      BT1[i] = f2b(v);
    }
  } else {
    if (i < 64 * K2P) {
      int o = i / K2P, k = i - o * K2P;
      float v = 0.f;
      if (o < 49) {
        if (k < 1225) v = Wcg21[k * 49 + o];
        else if (k < 2450) v = Wcg22[(k - 1225) * 49 + o];
      }
      BT2[i] = f2b(v);
    }
  }
}

// ---------------- per-node channel mean ----------------
__global__ __launch_bounds__(256) void node_mean_kernel(const float* __restrict__ x,
                                                        float* __restrict__ xmean) {
  int row = blockIdx.x * 4 + (threadIdx.x >> 6);
  int lane = threadIdx.x & 63;
  const float* p = x + (long)row * CC;
  float s = p[lane] + p[lane + 64];
  for (int off = 32; off > 0; off >>= 1) s += __shfl_down(s, off);
  if (lane == 0) xmean[row] = s * (1.0f / 128.0f);
}

// ---------------- P1[e][k] = xm_i * ym_j (k = i*49+j), bf16, zero-pad ----------------
__global__ __launch_bounds__(256) void build_p1_kernel(
    const float* __restrict__ xmean, const int* __restrict__ eidx, bf16* __restrict__ P1) {
  __shared__ float sxm[49], sym[49];
  int e = blockIdx.x, tid = threadIdx.x;
  int s = eidx[e], d = eidx[EE + e];
  if (tid < 49) { sxm[tid] = xmean[s * 49 + tid]; sym[tid] = xmean[d * 49 + tid]; }
  __syncthreads();
  for (int idx = tid; idx < K1P; idx += 256) {
    float v = 0.f;
    if (idx < 2401) { int i = idx / 49, j = idx - i * 49; v = sxm[i] * sym[j]; }
    P1[(long)e * K1P + idx] = f2b(v);
  }
}

// ---------------- P2[e][k]: k<1225: xm_i*mid_m; k<2450: ym_i*mid_m; pad 0 ----------------
__global__ __launch_bounds__(256) void build_p2_kernel(
    const float* __restrict__ xmean, const float* __restrict__ mid,
    const int* __restrict__ eidx, bf16* __restrict__ P2) {
  __shared__ float sxm[49], sym[49], smid[25];
  int e = blockIdx.x, tid = threadIdx.x;
  int s = eidx[e], d = eidx[EE + e];
  if (tid < 49) { sxm[tid] = xmean[s * 49 + tid]; sym[tid] = xmean[d * 49 + tid]; }
  if (tid >= 64 && tid < 89) smid[tid - 64] = mid[e * 32 + tid - 64];
  __syncthreads();
  for (int idx = tid; idx < K2P; idx += 256) {
    float v = 0.f;
    if (idx < 1225) { int i = idx / 25, m = idx - i * 25; v = sxm[i] * smid[m]; }
    else if (idx < 2450) { int kk = idx - 1225; int i = kk / 25, m = kk - i * 25; v = sym[i] * smid[m]; }
    P2[(long)e * K2P + idx] = f2b(v);
  }
}

// ---------------- small-N MFMA GEMM: C[M][NI*16] = A[M][K]bf16 @ BT[NI*16][K]^T ----------------
template <int NI>
__global__ __launch_bounds__(256) void gemm_smalln(
    const bf16* __restrict__ A, const bf16* __restrict__ BT,
    float* __restrict__ C, int K) {
  __shared__ short As[64 * 64];
  __shared__ short Bs[NI * 16 * 64];
  const int tid = threadIdx.x, w = tid >> 6, lane = tid & 63;
  const int lm = lane & 15, q = lane >> 4;
  const int bm = blockIdx.x * 64;
  f32x4 acc[NI];
#pragma unroll
  for (int ni = 0; ni < NI; ++ni) acc[ni] = (f32x4){0.f, 0.f, 0.f, 0.f};
  for (int k0 = 0; k0 < K; k0 += 64) {
    __syncthreads();
#pragma unroll
    for (int it = 0; it < 2; ++it) {
      int lc = it * 256 + tid;
      int m = lc >> 3, k8 = lc & 7;
      uint4 v = *(const uint4*)((const char*)A + ((long)(bm + m) * K + k0 + k8 * 8) * 2);
      *(uint4*)&As[(m * 8 + (k8 ^ (m & 7))) * 8] = v;
    }
#pragma unroll
    for (int it = 0; it < NI / 2; ++it) {
      int lc = it * 256 + tid;
      int n = lc >> 3, k8 = lc & 7;
      uint4 v = *(const uint4*)((const char*)BT + ((long)n * K + k0 + k8 * 8) * 2);
      *(uint4*)&Bs[(n * 8 + (k8 ^ (n & 7))) * 8] = v;
    }
    __syncthreads();
#pragma unroll
    for (int ks = 0; ks < 2; ++ks) {
      short8 af = *(const short8*)&As[(w * 16 + lm) * 64 + ((ks * 4 + q) ^ (lm & 7)) * 8];
#pragma unroll
      for (int ni = 0; ni < NI; ++ni) {
        short8 bfr = *(const short8*)&Bs[(ni * 16 + lm) * 64 + ((ks * 4 + q) ^ (lm & 7)) * 8];
        acc[ni] = __builtin_amdgcn_mfma_f32_16x16x32_bf16(af, bfr, acc[ni], 0, 0, 0);
      }
    }
  }
#pragma unroll
  for (int ni = 0; ni < NI; ++ni) {
    int col = ni * 16 + lm;
#pragma unroll
    for (int r = 0; r < 4; ++r) {
      int row = bm + w * 16 + q * 4 + r;
      C[(long)row * (NI * 16) + col] = acc[ni][r];
    }
  }
}

// ---------------- feat build -> bf16 [8192][2112] (rows e, 4096+e), pad cols 2064..2111 = 0 ----------------
__global__ __launch_bounds__(256) void build_feat_kernel(
    const float* __restrict__ x, const float* __restrict__ x_glovec,
    const float* __restrict__ wig_node, const int* __restrict__ eidx,
    bf16* __restrict__ featst) {
  __shared__ float wig[256];
  __shared__ float xa[2048], xb[2048], tmp[2048];
  int e = blockIdx.x, tid = threadIdx.x;
  int s = eidx[e], d = eidx[EE + e];
  wig[tid] = wig_node[e * 256 + tid];
  if (tid < 48) {
    featst[(long)e * 2112 + 2064 + tid] = f2b(0.f);
    featst[(long)(EE + e) * 2112 + 2064 + tid] = f2b(0.f);
  }
  for (int idx = tid; idx < 2048; idx += 256) {
    int l = idx >> 7, c = idx & 127;
    xa[idx] = x[((long)s * LL + l) * CC + c];
    xb[idx] = x[((long)d * LL + l) * CC + c];
  }
  __syncthreads();
  for (int idx = tid; idx < 2048; idx += 256) {
    int i = idx >> 7, c = idx & 127;
    float a = 0.f;
#pragma unroll
    for (int j = 0; j < 16; ++j) a += wig[j * 16 + i] * xa[j * 128 + c];
    tmp[idx] = a;
    featst[(long)e * 2112 + i * 129 + c] = f2b(a);
  }
  __syncthreads();
  if (tid < 16) {
    float m = 0.f;
    for (int c = 0; c < 128; ++c) m += tmp[tid * 128 + c];
    featst[(long)e * 2112 + tid * 129 + 128] = f2b(m * (1.0f / 128.0f) * x_glovec[(long)d * 16 + tid]);
  }
  __syncthreads();
  for (int idx = tid; idx < 2048; idx += 256) {
    int i = idx >> 7, c = idx & 127;
    float a = 0.f;
#pragma unroll
    for (int j = 0; j < 16; ++j) a += wig[j * 16 + i] * xb[j * 128 + c];
    tmp[idx] = a;
    featst[(long)(EE + e) * 2112 + i * 129 + c] = f2b(a);
  }
  __syncthreads();
  if (tid < 16) {
    float m = 0.f;
    for (int c = 0; c < 128; ++c) m += tmp[tid * 128 + c];
    featst[(long)(EE + e) * 2112 + tid * 129 + 128] = f2b(m * (1.0f / 128.0f) * x_glovec[(long)s * 16 + tid]);
  }
}

// ---------------- fp32 tiled GEMM (only for tiny xe GEMM) ----------------
__global__ __launch_bounds__(256) void gemm_f32_silu(
    const float* __restrict__ A, const float* __restrict__ B,
    const float* __restrict__ bias, float* __restrict__ C, int M, int N, int K) {
  __shared__ float As[16][68];
  __shared__ float Bs[16][64];
  const int tid = threadIdx.x;
  const int bm = blockIdx.x * 64, bn = blockIdx.y * 64;
  const int tx = tid & 15, ty = tid >> 4;
  const int ar = tid >> 2, ak = (tid & 3) * 4;
  const int br = tid >> 4, bc = (tid & 15) * 4;
  float acc[4][4] = {};
  const float* Ap = A + (long)(bm + ar) * K + ak;
  const float* Bp = B + (long)br * N + bn + bc;
  for (int k0 = 0; k0 < K; k0 += 16) {
    const float4 av = *(const float4*)(Ap + k0);
    const float4 bv = *(const float4*)(Bp + (long)k0 * N);
    __syncthreads();
    As[ak + 0][ar] = av.x; As[ak + 1][ar] = av.y;
    As[ak + 2][ar] = av.z; As[ak + 3][ar] = av.w;
    *(float4*)&Bs[br][bc] = bv;
    __syncthreads();
#pragma unroll
    for (int k = 0; k < 16; ++k) {
      const float4 a = *(const float4*)&As[k][ty * 4];
      const float4 b = *(const float4*)&Bs[k][tx * 4];
      acc[0][0] += a.x * b.x; acc[0][1] += a.x * b.y; acc[0][2] += a.x * b.z; acc[0][3] += a.x * b.w;
      acc[1][0] += a.y * b.x; acc[1][1] += a.y * b.y; acc[1][2] += a.y * b.z; acc[1][3] += a.y * b.w;
      acc[2][0] += a.z * b.x; acc[2][1] += a.z * b.y; acc[2][2] += a.z * b.z; acc[2][3] += a.z * b.w;
      acc[3][0] += a.w * b.x; acc[3][1] += a.w * b.y; acc[3][2] += a.w * b.z; acc[3][3] += a.w * b.w;
    }
  }
#pragma unroll
  for (int i = 0; i < 4; ++i) {
    int row = bm + ty * 4 + i;
#pragma unroll
    for (int j = 0; j < 4; ++j) {
      int col = bn + tx * 4 + j;
      C[(long)row * N + col] = siluf(acc[i][j] + bias[col]);
    }
  }
}

// ---------------- bf16 MFMA GEMM: C = epi(A[MxK]bf16 @ BT[NxK]bf16^T + bias) ----------------
template <int BM, bool SILU, bool XE, bool OUT_BF16>
__global__ __launch_bounds__(256) void gemm_mfma(
    const bf16* __restrict__ A, const bf16* __restrict__ B0, const bf16* __restrict__ B1,
    const float* __restrict__ bias0, const float* __restrict__ bias1,
    const float* __restrict__ xe, void* __restrict__ Cout,
    int M, int N, int K, int half) {
  constexpr int MI = BM / 32;
  __shared__ short As[BM * 64];
  __shared__ short Bs[128 * 64];
  const int tid = threadIdx.x;
  const int w = tid >> 6, lane = tid & 63;
  const int lm = lane & 15, q = lane >> 4;
  const int bm = blockIdx.x * BM, bn = blockIdx.y * 128;
  const int wm = (w & 1) * (BM / 2), wn = (w >> 1) * 64;
  const bf16* Bp = (bm < half) ? B0 : B1;
  const float* bias = (bm < half) ? bias0 : bias1;

  f32x4 acc[MI][4];
#pragma unroll
  for (int mi = 0; mi < MI; ++mi)
#pragma unroll
    for (int ni = 0; ni < 4; ++ni) acc[mi][ni] = (f32x4){0.f, 0.f, 0.f, 0.f};

  for (int k0 = 0; k0 < K; k0 += 64) {
    __syncthreads();
#pragma unroll
    for (int it = 0; it < BM / 32; ++it) {
      int lc = it * 256 + tid;
      int m = lc >> 3, k8 = lc & 7;
      uint4 v = *(const uint4*)((const char*)A + ((long)(bm + m) * K + k0 + k8 * 8) * 2);
      *(uint4*)&As[(m * 8 + (k8 ^ (m & 7))) * 8] = v;
    }
#pragma unroll
    for (int it = 0; it < 4; ++it) {
      int lc = it * 256 + tid;
      int n = lc >> 3, k8 = lc & 7;
      uint4 v = *(const uint4*)((const char*)Bp + ((long)(bn + n) * K + k0 + k8 * 8) * 2);
      *(uint4*)&Bs[(n * 8 + (k8 ^ (n & 7))) * 8] = v;
    }
    __syncthreads();
#pragma unroll
    for (int ks = 0; ks < 2; ++ks) {
      short8 af[MI], bfr[4];
#pragma unroll
      for (int mi = 0; mi < MI; ++mi) {
        int row = wm + mi * 16 + lm;
        af[mi] = *(const short8*)&As[row * 64 + ((ks * 4 + q) ^ (lm & 7)) * 8];
      }
#pragma unroll
      for (int ni = 0; ni < 4; ++ni) {
        int row = wn + ni * 16 + lm;
        bfr[ni] = *(const short8*)&Bs[row * 64 + ((ks * 4 + q) ^ (lm & 7)) * 8];
      }
#pragma unroll
      for (int mi = 0; mi < MI; ++mi)
#pragma unroll
        for (int ni = 0; ni < 4; ++ni)
          acc[mi][ni] = __builtin_amdgcn_mfma_f32_16x16x32_bf16(af[mi], bfr[ni], acc[mi][ni], 0, 0, 0);
    }
  }
#pragma unroll
  for (int mi = 0; mi < MI; ++mi) {
#pragma unroll
    for (int ni = 0; ni < 4; ++ni) {
      int col = bn + wn + ni * 16 + lm;
      float bcol = bias[col];
#pragma unroll
      for (int r = 0; r < 4; ++r) {
        int row = bm + wm + mi * 16 + q * 4 + r;
        float v = acc[mi][ni][r] + bcol;
        if (SILU) v = siluf(v);
        if (XE) v *= xe[(row / 3) * HH + col];
        if (OUT_BF16) ((bf16*)Cout)[(long)row * N + col] = f2b(v);
        else ((float*)Cout)[(long)row * N + col] = v;
      }
    }
  }
}

// ---------------- fused: sh = wig_node @ (o1+o2); z = 2(xs+xt)+asum+pad(sh); msg = wigner @ z ------------
// 512 threads / edge, single full-width pass. Split-bf16 (hi/lo, 3 products) keeps fp32-equivalent accuracy.
// LDS ~80 KB -> 2 blocks/CU (16 waves/CU). All global loads float4-vectorized.
__global__ __launch_bounds__(512, 4) void rotate_msg_fused_kernel(
    const float* __restrict__ x, const float* __restrict__ wigner,
    const int* __restrict__ eidx, const float* __restrict__ asum,
    const float* __restrict__ o1, const float* __restrict__ o2,
    const float* __restrict__ wig_node, bf16* __restrict__ msg) {
  __shared__ bf16 Ah[48 * 64], Al[48 * 64];        // wigner hi/lo, XOR-swizzled rows (12 KB)
  __shared__ bf16 zTh[128 * 64], zTl[128 * 64];    // z^T hi/lo, GEMM-B layout (32 KB)
  __shared__ float z[49 * 132];                    // fp32 z, stride 132 -> (b+c)%32 banks, 2-way (25.9 KB)
  __shared__ float osum[16 * 128];                 // o1+o2 (8 KB)
  __shared__ float wig[256];
  __shared__ float as_s[49];
  const int e = blockIdx.x, tid = threadIdx.x;
  const int s = eidx[e], d = eidx[EE + e];
  const int w = tid >> 6, lane = tid & 63;
  const int lm = lane & 15, q = lane >> 4;

  // ---- P1: stage everything (independent vector loads) ----
  if (tid < 49) as_s[tid] = asum[e * 64 + tid];
  if (tid >= 64 && tid < 128) {
    int i = tid - 64;
    *(float4*)&wig[i * 4] = *(const float4*)&wig_node[(long)e * 256 + i * 4];
  }
  {  // osum = o1[e] + o2[e]: exactly one float4 per thread
    float4 a = *(const float4*)&o1[(long)e * 2048 + tid * 4];
    float4 b = *(const float4*)&o2[(long)e * 2048 + tid * 4];
    float4 v; v.x = a.x + b.x; v.y = a.y + b.y; v.z = a.z + b.z; v.w = a.w + b.w;
    *(float4*)&osum[tid * 4] = v;
  }
  for (int i = tid; i < 48 * 15; i += 512) {  // A zero-pad k in [49,64)
    int m = i / 15, k = 49 + (i - m * 15);
    int off = m * 64 + (((k >> 3) ^ (m & 7)) << 3) + (k & 7);
    Ah[off] = f2b(0.f); Al[off] = f2b(0.f);
  }
  for (int i4 = tid; i4 < 588; i4 += 512) {   // wigner -> Ah/Al (float4 loads)
    float4 v4 = *(const float4*)&wigner[(long)e * 2352 + i4 * 4];
    int i = i4 * 4;
    int m = i / 49, k = i - m * 49;
    float vv[4] = {v4.x, v4.y, v4.z, v4.w};
#pragma unroll
    for (int j = 0; j < 4; ++j) {
      bf16 h = f2b(vv[j]);
      bf16 l = f2b(vv[j] - __bfloat162float(h));
      int off = m * 64 + (((k >> 3) ^ (m & 7)) << 3) + (k & 7);
      Ah[off] = h; Al[off] = l;
      if (++k == 49) { k = 0; ++m; }
    }
  }
  __syncthreads();

  // ---- P2: z build, rotback's sh fused inline for rows l<16 ----
  {
    const float* xs = x + (long)s * (LL * CC);
    const float* xt = x + (long)d * (LL * CC);
    for (int i4 = tid; i4 < 49 * 32; i4 += 512) {
      int l = i4 >> 5, c4 = i4 & 31;
      float4 a = *(const float4*)&xs[l * 128 + c4 * 4];
      float4 b = *(const float4*)&xt[l * 128 + c4 * 4];
      float ad = as_s[l];
      float4 v;
      v.x = 2.f * (a.x + b.x) + ad;
      v.y = 2.f * (a.y + b.y) + ad;
      v.z = 2.f * (a.z + b.z) + ad;
      v.w = 2.f * (a.w + b.w) + ad;
      if (l < 16) {
#pragma unroll
        for (int j = 0; j < 16; ++j) {
          float wv = wig[l * 16 + j];                       // broadcast
          float4 o = *(const float4*)&osum[j * 128 + c4 * 4];
          v.x += wv * o.x; v.y += wv * o.y; v.z += wv * o.z; v.w += wv * o.w;
        }
      }
      *(float4*)&z[l * 132 + c4 * 4] = v;
    }
  }
  __syncthreads();

  // ---- P3: transpose + hi/lo split (reads 2-way bank, writes 2-way) ----
  {
    int b = lane;
#pragma unroll
    for (int i = 0; i < 16; ++i) {
      int c = w * 16 + i;
      float v = (b < 49) ? z[b * 132 + c] : 0.f;
      bf16 h = f2b(v);
      bf16 l = f2b(v - __bfloat162float(h));
      int off = c * 64 + (((b >> 3) ^ (c & 7)) << 3) + (b & 7);
      zTh[off] = h; zTl[off] = l;
    }
  }
  __syncthreads();

  // ---- P4: MFMA (wave w -> n-tile w, m-tiles = NY taps) + store ----
  short8 ah[3][2], alo[3][2], bh[2], bl[2];
#pragma unroll
  for (int mi = 0; mi < 3; ++mi)
#pragma unroll
    for (int ks = 0; ks < 2; ++ks) {
      int off = (mi * 16 + lm) * 64 + (((ks * 4 + q) ^ (lm & 7)) << 3);
      ah[mi][ks] = *(const short8*)&Ah[off];
      alo[mi][ks] = *(const short8*)&Al[off];
    }
#pragma unroll
  for (int ks = 0; ks < 2; ++ks) {
    int off = (w * 16 + lm) * 64 + (((ks * 4 + q) ^ (lm & 7)) << 3);
    bh[ks] = *(const short8*)&zTh[off];
    bl[ks] = *(const short8*)&zTl[off];
  }
  f32x4 acc[3];
#pragma unroll
  for (int mi = 0; mi < 3; ++mi) acc[mi] = (f32x4){0.f, 0.f, 0.f, 0.f};
#pragma unroll
  for (int mi = 0; mi < 3; ++mi)
#pragma unroll
    for (int ks = 0; ks < 2; ++ks) {
      acc[mi] = __builtin_amdgcn_mfma_f32_16x16x32_bf16(ah[mi][ks], bh[ks], acc[mi], 0, 0, 0);
      acc[mi] = __builtin_amdgcn_mfma_f32_16x16x32_bf16(ah[mi][ks], bl[ks], acc[mi], 0, 0, 0);
      acc[mi] = __builtin_amdgcn_mfma_f32_16x16x32_bf16(alo[mi][ks], bh[ks], acc[mi], 0, 0, 0);
    }
  {
    int c = w * 16 + lm;
#pragma unroll
    for (int mi = 0; mi < 3; ++mi) {
      long base = ((long)e * 3 + mi) * 2048 + c;
#pragma unroll
      for (int r = 0; r < 4; ++r)
        msg[base + (q * 4 + r) * 128] = f2b(acc[mi][r]);
    }
  }
}

// ---------------- out = INV_SQRT_3 * wigner_inv @ mean_ny(m2) ----------------
__global__ __launch_bounds__(256) void out_kernel(
    const float* __restrict__ m2, const float* __restrict__ wigner_inv,
    float* __restrict__ out) {
  __shared__ float mr[2048];
  __shared__ float wv[784];
  int e = blockIdx.x, tid = threadIdx.x;
  for (int idx = tid; idx < 2048; idx += 256)
    mr[idx] = (m2[((long)e * 3 + 0) * 2048 + idx] + m2[((long)e * 3 + 1) * 2048 + idx] +
               m2[((long)e * 3 + 2) * 2048 + idx]) * (1.0f / 3.0f);
  for (int idx = tid; idx < 784; idx += 256) wv[idx] = wigner_inv[(long)e * 784 + idx];
  __syncthreads();
  for (int idx = tid; idx < 6272; idx += 256) {
    int bq = idx >> 7, c = idx & 127;
    const float* wp = wv + bq * 16;
    float a = 0.f;
#pragma unroll
    for (int r = 0; r < 16; ++r) a += wp[r] * mr[r * 128 + c];
    out[(long)e * 6272 + idx] = a * 0.57735026918962576f;
  }
}

// ---------------- host side ----------------
extern "C" void kernel_launch(void* const* d_in, const int* in_sizes, int n_in,
                              void* d_out, int out_size, void* d_ws, size_t ws_size,
                              hipStream_t stream) {
  (void)in_sizes; (void)n_in; (void)out_size; (void)ws_size;
  const float* x        = (const float*)d_in[0];
  const float* x_glovec = (const float*)d_in[2];
  const float* x_edge   = (const float*)d_in[3];
  const int*   eidx     = (const int*)d_in[4];
  const float* W_cg1   = (const float*)d_in[8];
  const float* W_cg21  = (const float*)d_in[9];
  const float* W_cg22  = (const float*)d_in[10];
  const float* Wn1a = (const float*)d_in[11];
  const float* bn1a = (const float*)d_in[12];
  const float* Wn1b = (const float*)d_in[13];
  const float* bn1b = (const float*)d_in[14];
  const float* Wn2a = (const float*)d_in[15];
  const float* bn2a = (const float*)d_in[16];
  const float* Wn2b = (const float*)d_in[17];
  const float* bn2b = (const float*)d_in[18];
  const float* Wd   = (const float*)d_in[19];
  const float* bd   = (const float*)d_in[20];
  const float* Wp1  = (const float*)d_in[21];
  const float* bp1  = (const float*)d_in[22];
  const float* Wp2  = (const float*)d_in[23];
  const float* bp2  = (const float*)d_in[24];
  const float* wigner     = (const float*)d_in[25];
  const float* wigner_inv = (const float*)d_in[26];
  const float* wig_node   = (const float*)d_in[27];

  char* W = (char*)d_ws;
  bf16*  featst = (bf16*)(W + 0);            // 8192 x 2112 bf16 (34.6 MB)
  float* ostack = (float*)(W + 34603008);    // 8192 x 2048 f32  (67 MB)
  float* m2     = (float*)(W + 0);           // alias: 12288 x 2048 f32 (100.7 MB)
  bf16*  msg    = (bf16*)(W + 135266304);    // 12288 x 2048 bf16 (50.3 MB)
  bf16*  P1     = (bf16*)(W + 135266304);    // alias in msg region: 4096 x 2432 bf16 (19.9 MB)
  bf16*  P2     = (bf16*)(W + 155189248);    // alias in msg region: 4096 x 2496 bf16 (20.4 MB)
  bf16*  hstack = (bf16*)(W + 185597952);    // 8192 x 128 bf16
  bf16*  m1     = (bf16*)(W + 187695104);    // 12288 x 128 bf16
  float* p_xe   = (float*)(W + 190840832);   // 4096 x 128 f32
  float* p_xmean= (float*)(W + 192937984);   // 100352 f32
  bf16*  BTa    = (bf16*)(W + 194142208);    // 2 x 128 x 2112
  bf16*  BTb    = (bf16*)(W + 195223552);    // 2 x 2048 x 128
  bf16*  BTp1   = (bf16*)(W + 196272128);    // 128 x 2048
  bf16*  BTp2   = (bf16*)(W + 196796416);    // 2048 x 128 (ends 197320704)
  float* p_asum = (float*)(W + 197320704);   // 4096 x 64 f32 (1 MB)
  float* p_mid  = (float*)(W + 198369280);   // 4096 x 32 f32 (512 KB)
  bf16*  BT1    = (bf16*)(W + 198893568);    // 32 x 2432 bf16 (152 KB)
  bf16*  BT2    = (bf16*)(W + 199049216);    // 64 x 2496 bf16 (312 KB; ends 199368704)

  TJobs tj;
  tj.j[0] = {Wn1a, BTa,            2064, 128, 2112};
  tj.j[1] = {Wn2a, BTa + 270336,   2064, 128, 2112};
  tj.j[2] = {Wn1b, BTb,            128, 2048, 128};
  tj.j[3] = {Wn2b, BTb + 262144,   128, 2048, 128};
  tj.j[4] = {Wp1,  BTp1,           2048, 128, 2048};
  tj.j[5] = {Wp2,  BTp2,           128, 2048, 128};
  transpose_cvt_kernel<<<dim3(1056, 6), 256, 0, stream>>>(tj);
  cg_prep_kernel<<<dim3(624, 2), 256, 0, stream>>>(W_cg1, W_cg21, W_cg22, BT1, BT2);

  node_mean_kernel<<<(NN * LL) / 4, 256, 0, stream>>>(x, p_xmean);
  // CG bilinears as outer-product GEMMs
  build_p1_kernel<<<EE, 256, 0, stream>>>(p_xmean, eidx, P1);
  gemm_smalln<2><<<EE / 64, 256, 0, stream>>>(P1, BT1, p_mid, K1P);
  build_p2_kernel<<<EE, 256, 0, stream>>>(p_xmean, p_mid, eidx, P2);
  gemm_smalln<4><<<EE / 64, 256, 0, stream>>>(P2, BT2, p_asum, K2P);

  gemm_f32_silu<<<dim3(EE / 64, 2), 256, 0, stream>>>(x_edge, Wd, bd, p_xe, EE, HH, 128);
  build_feat_kernel<<<EE, 256, 0, stream>>>(x, x_glovec, wig_node, eidx, featst);
  // h = silu(feat @ Wna): M=8192, N=128, K=2112, stacked weights
  gemm_mfma<64, true, false, true><<<dim3(128, 1), 256, 0, stream>>>(
      featst, BTa, BTa + 270336, bn1a, bn2a, nullptr, hstack, 8192, 128, 2112, 4096);
  // o = silu(h @ Wnb): M=8192, N=2048, K=128, stacked weights, fp32 out
  gemm_mfma<128, true, false, false><<<dim3(64, 16), 256, 0, stream>>>(
      hstack, BTb, BTb + 262144, bn1b, bn2b, nullptr, ostack, 8192, 2048, 128, 4096);
  // fused rotback + z-build + msg GEMM
  rotate_msg_fused_kernel<<<EE, 512, 0, stream>>>(
      x, wigner, eidx, p_asum, ostack, ostack + (long)4096 * 2048, wig_node, msg);
  // m1 = silu(msg @ Wp1) * xe: M=12288, N=128, K=2048, bf16 out
  gemm_mfma<64, true, true, true><<<dim3(192, 1), 256, 0, stream>>>(
      msg, BTp1, BTp1, bp1, bp1, p_xe, m1, 12288, 128, 2048, 1 << 30);
  // m2 = silu(m1 @ Wp2): M=12288, N=2048, K=128, fp32 out
  gemm_mfma<128, true, false, false><<<dim3(96, 16), 256, 0, stream>>>(
      m1, BTp2, BTp2, bp2, bp2, nullptr, m2, 12288, 2048, 128, 1 << 30);
  out_kernel<<<EE, 256, 0, stream>>>(m2, wigner_inv, (float*)d_out);
}

// Round 3
// 569.594 us; speedup vs baseline: 1.2439x; 1.0122x over previous
//
#include <hip/hip_runtime.h>
#include <hip/hip_bf16.h>

typedef __hip_bfloat16 bf16;
typedef __attribute__((ext_vector_type(8))) short short8;
typedef __attribute__((ext_vector_type(4))) float f32x4;

#define NN 2048
#define EE 4096
#define LL 49
#define LRR 16
#define NYY 3
#define CC 128
#define HH 128

#define K1P 2432   // 2401 padded to x64 (P1 / BT1 K)
#define K2P 2496   // 2450 padded to x64 (P2 / BT2 K)

__device__ __forceinline__ float siluf(float v) { return v * (1.0f / (1.0f + __expf(-v))); }
__device__ __forceinline__ bf16 f2b(float v) { return __float2bfloat16(v); }
__device__ __forceinline__ float getc(float4 v, int i) {
  return i == 0 ? v.x : i == 1 ? v.y : i == 2 ? v.z : v.w;
}

// ---------------- weight convert + transpose: out[n*Kp+k] = bf16(in[k*N+n]), zero-pad k>=K ----------------
struct TJob { const float* in; bf16* out; int K, N, Kp; };
struct TJobs { TJob j[6]; };

__global__ __launch_bounds__(256) void transpose_cvt_kernel(TJobs jobs) {
  TJob jb = jobs.j[blockIdx.y];
  int i = blockIdx.x * 256 + threadIdx.x;
  if (i < jb.N * jb.Kp) {
    int n = i / jb.Kp, k = i - n * jb.Kp;
    jb.out[i] = (k < jb.K) ? f2b(jb.in[(long)k * jb.N + n]) : f2b(0.f);
  }
}

// ---------------- CG weight prep: BT1[32][K1P], BT2[64][K2P] (transposed, bf16, zero-padded) ----------------
__global__ __launch_bounds__(256) void cg_prep_kernel(
    const float* __restrict__ Wcg1, const float* __restrict__ Wcg21,
    const float* __restrict__ Wcg22, bf16* __restrict__ BT1, bf16* __restrict__ BT2) {
  int i = blockIdx.x * 256 + threadIdx.x;
  if (blockIdx.y == 0) {
    if (i < 32 * K1P) {
      int o = i / K1P, k = i - o * K1P;
      float v = (o < 25 && k < 2401) ? Wcg1[k * 25 + o] : 0.f;
      BT1[i] = f2b(v);
    }
  } else {
    if (i < 64 * K2P) {
      int o = i / K2P, k = i - o * K2P;
      float v = 0.f;
      if (o < 49) {
        if (k < 1225) v = Wcg21[k * 49 + o];
        else if (k < 2450) v = Wcg22[(k - 1225) * 49 + o];
      }
      BT2[i] = f2b(v);
    }
  }
}

// ---------------- per-node channel mean ----------------
__global__ __launch_bounds__(256) void node_mean_kernel(const float* __restrict__ x,
                                                        float* __restrict__ xmean) {
  int row = blockIdx.x * 4 + (threadIdx.x >> 6);
  int lane = threadIdx.x & 63;
  const float* p = x + (long)row * CC;
  float s = p[lane] + p[lane + 64];
  for (int off = 32; off > 0; off >>= 1) s += __shfl_down(s, off);
  if (lane == 0) xmean[row] = s * (1.0f / 128.0f);
}

// ---------------- P1[e][k] = xm_i * ym_j (k = i*49+j), bf16, zero-pad ----------------
__global__ __launch_bounds__(256) void build_p1_kernel(
    const float* __restrict__ xmean, const int* __restrict__ eidx, bf16* __restrict__ P1) {
  __shared__ float sxm[49], sym[49];
  int e = blockIdx.x, tid = threadIdx.x;
  int s = eidx[e], d = eidx[EE + e];
  if (tid < 49) { sxm[tid] = xmean[s * 49 + tid]; sym[tid] = xmean[d * 49 + tid]; }
  __syncthreads();
  for (int idx = tid; idx < K1P; idx += 256) {
    float v = 0.f;
    if (idx < 2401) { int i = idx / 49, j = idx - i * 49; v = sxm[i] * sym[j]; }
    P1[(long)e * K1P + idx] = f2b(v);
  }
}

// ---------------- P2[e][k]: k<1225: xm_i*mid_m; k<2450: ym_i*mid_m; pad 0 ----------------
__global__ __launch_bounds__(256) void build_p2_kernel(
    const float* __restrict__ xmean, const float* __restrict__ mid,
    const int* __restrict__ eidx, bf16* __restrict__ P2) {
  __shared__ float sxm[49], sym[49], smid[25];
  int e = blockIdx.x, tid = threadIdx.x;
  int s = eidx[e], d = eidx[EE + e];
  if (tid < 49) { sxm[tid] = xmean[s * 49 + tid]; sym[tid] = xmean[d * 49 + tid]; }
  if (tid >= 64 && tid < 89) smid[tid - 64] = mid[e * 32 + tid - 64];
  __syncthreads();
  for (int idx = tid; idx < K2P; idx += 256) {
    float v = 0.f;
    if (idx < 1225) { int i = idx / 25, m = idx - i * 25; v = sxm[i] * smid[m]; }
    else if (idx < 2450) { int kk = idx - 1225; int i = kk / 25, m = kk - i * 25; v = sym[i] * smid[m]; }
    P2[(long)e * K2P + idx] = f2b(v);
  }
}

// ---------------- small-N MFMA GEMM: C[M][NI*16] = A[M][K]bf16 @ BT[NI*16][K]^T ----------------
template <int NI>
__global__ __launch_bounds__(256) void gemm_smalln(
    const bf16* __restrict__ A, const bf16* __restrict__ BT,
    float* __restrict__ C, int K) {
  __shared__ short As[64 * 64];
  __shared__ short Bs[NI * 16 * 64];
  const int tid = threadIdx.x, w = tid >> 6, lane = tid & 63;
  const int lm = lane & 15, q = lane >> 4;
  const int bm = blockIdx.x * 64;
  f32x4 acc[NI];
#pragma unroll
  for (int ni = 0; ni < NI; ++ni) acc[ni] = (f32x4){0.f, 0.f, 0.f, 0.f};
  for (int k0 = 0; k0 < K; k0 += 64) {
    __syncthreads();
#pragma unroll
    for (int it = 0; it < 2; ++it) {
      int lc = it * 256 + tid;
      int m = lc >> 3, k8 = lc & 7;
      uint4 v = *(const uint4*)((const char*)A + ((long)(bm + m) * K + k0 + k8 * 8) * 2);
      *(uint4*)&As[(m * 8 + (k8 ^ (m & 7))) * 8] = v;
    }
#pragma unroll
    for (int it = 0; it < NI / 2; ++it) {
      int lc = it * 256 + tid;
      int n = lc >> 3, k8 = lc & 7;
      uint4 v = *(const uint4*)((const char*)BT + ((long)n * K + k0 + k8 * 8) * 2);
      *(uint4*)&Bs[(n * 8 + (k8 ^ (n & 7))) * 8] = v;
    }
    __syncthreads();
#pragma unroll
    for (int ks = 0; ks < 2; ++ks) {
      short8 af = *(const short8*)&As[(w * 16 + lm) * 64 + ((ks * 4 + q) ^ (lm & 7)) * 8];
#pragma unroll
      for (int ni = 0; ni < NI; ++ni) {
        short8 bfr = *(const short8*)&Bs[(ni * 16 + lm) * 64 + ((ks * 4 + q) ^ (lm & 7)) * 8];
        acc[ni] = __builtin_amdgcn_mfma_f32_16x16x32_bf16(af, bfr, acc[ni], 0, 0, 0);
      }
    }
  }
#pragma unroll
  for (int ni = 0; ni < NI; ++ni) {
    int col = ni * 16 + lm;
#pragma unroll
    for (int r = 0; r < 4; ++r) {
      int row = bm + w * 16 + q * 4 + r;
      C[(long)row * (NI * 16) + col] = acc[ni][r];
    }
  }
}

// ---------------- feat build -> bf16 [8192][2112] (rows e, 4096+e), pad cols 2064..2111 = 0 ----------------
__global__ __launch_bounds__(256) void build_feat_kernel(
    const float* __restrict__ x, const float* __restrict__ x_glovec,
    const float* __restrict__ wig_node, const int* __restrict__ eidx,
    bf16* __restrict__ featst) {
  __shared__ float wig[256];
  __shared__ float xa[2048], xb[2048], tmp[2048];
  int e = blockIdx.x, tid = threadIdx.x;
  int s = eidx[e], d = eidx[EE + e];
  wig[tid] = wig_node[e * 256 + tid];
  if (tid < 48) {
    featst[(long)e * 2112 + 2064 + tid] = f2b(0.f);
    featst[(long)(EE + e) * 2112 + 2064 + tid] = f2b(0.f);
  }
  for (int idx = tid; idx < 2048; idx += 256) {
    int l = idx >> 7, c = idx & 127;
    xa[idx] = x[((long)s * LL + l) * CC + c];
    xb[idx] = x[((long)d * LL + l) * CC + c];
  }
  __syncthreads();
  for (int idx = tid; idx < 2048; idx += 256) {
    int i = idx >> 7, c = idx & 127;
    float a = 0.f;
#pragma unroll
    for (int j = 0; j < 16; ++j) a += wig[j * 16 + i] * xa[j * 128 + c];
    tmp[idx] = a;
    featst[(long)e * 2112 + i * 129 + c] = f2b(a);
  }
  __syncthreads();
  if (tid < 16) {
    float m = 0.f;
    for (int c = 0; c < 128; ++c) m += tmp[tid * 128 + c];
    featst[(long)e * 2112 + tid * 129 + 128] = f2b(m * (1.0f / 128.0f) * x_glovec[(long)d * 16 + tid]);
  }
  __syncthreads();
  for (int idx = tid; idx < 2048; idx += 256) {
    int i = idx >> 7, c = idx & 127;
    float a = 0.f;
#pragma unroll
    for (int j = 0; j < 16; ++j) a += wig[j * 16 + i] * xb[j * 128 + c];
    tmp[idx] = a;
    featst[(long)(EE + e) * 2112 + i * 129 + c] = f2b(a);
  }
  __syncthreads();
  if (tid < 16) {
    float m = 0.f;
    for (int c = 0; c < 128; ++c) m += tmp[tid * 128 + c];
    featst[(long)(EE + e) * 2112 + tid * 129 + 128] = f2b(m * (1.0f / 128.0f) * x_glovec[(long)s * 16 + tid]);
  }
}

// ---------------- fp32 tiled GEMM (only for tiny xe GEMM) ----------------
__global__ __launch_bounds__(256) void gemm_f32_silu(
    const float* __restrict__ A, const float* __restrict__ B,
    const float* __restrict__ bias, float* __restrict__ C, int M, int N, int K) {
  __shared__ float As[16][68];
  __shared__ float Bs[16][64];
  const int tid = threadIdx.x;
  const int bm = blockIdx.x * 64, bn = blockIdx.y * 64;
  const int tx = tid & 15, ty = tid >> 4;
  const int ar = tid >> 2, ak = (tid & 3) * 4;
  const int br = tid >> 4, bc = (tid & 15) * 4;
  float acc[4][4] = {};
  const float* Ap = A + (long)(bm + ar) * K + ak;
  const float* Bp = B + (long)br * N + bn + bc;
  for (int k0 = 0; k0 < K; k0 += 16) {
    const float4 av = *(const float4*)(Ap + k0);
    const float4 bv = *(const float4*)(Bp + (long)k0 * N);
    __syncthreads();
    As[ak + 0][ar] = av.x; As[ak + 1][ar] = av.y;
    As[ak + 2][ar] = av.z; As[ak + 3][ar] = av.w;
    *(float4*)&Bs[br][bc] = bv;
    __syncthreads();
#pragma unroll
    for (int k = 0; k < 16; ++k) {
      const float4 a = *(const float4*)&As[k][ty * 4];
      const float4 b = *(const float4*)&Bs[k][tx * 4];
      acc[0][0] += a.x * b.x; acc[0][1] += a.x * b.y; acc[0][2] += a.x * b.z; acc[0][3] += a.x * b.w;
      acc[1][0] += a.y * b.x; acc[1][1] += a.y * b.y; acc[1][2] += a.y * b.z; acc[1][3] += a.y * b.w;
      acc[2][0] += a.z * b.x; acc[2][1] += a.z * b.y; acc[2][2] += a.z * b.z; acc[2][3] += a.z * b.w;
      acc[3][0] += a.w * b.x; acc[3][1] += a.w * b.y; acc[3][2] += a.w * b.z; acc[3][3] += a.w * b.w;
    }
  }
#pragma unroll
  for (int i = 0; i < 4; ++i) {
    int row = bm + ty * 4 + i;
#pragma unroll
    for (int j = 0; j < 4; ++j) {
      int col = bn + tx * 4 + j;
      C[(long)row * N + col] = siluf(acc[i][j] + bias[col]);
    }
  }
}

// ---------------- bf16 MFMA GEMM: C = epi(A[MxK]bf16 @ BT[NxK]bf16^T + bias) ----------------
template <int BM, bool SILU, bool XE, bool OUT_BF16>
__global__ __launch_bounds__(256) void gemm_mfma(
    const bf16* __restrict__ A, const bf16* __restrict__ B0, const bf16* __restrict__ B1,
    const float* __restrict__ bias0, const float* __restrict__ bias1,
    const float* __restrict__ xe, void* __restrict__ Cout,
    int M, int N, int K, int half) {
  constexpr int MI = BM / 32;
  __shared__ short As[BM * 64];
  __shared__ short Bs[128 * 64];
  const int tid = threadIdx.x;
  const int w = tid >> 6, lane = tid & 63;
  const int lm = lane & 15, q = lane >> 4;
  const int bm = blockIdx.x * BM, bn = blockIdx.y * 128;
  const int wm = (w & 1) * (BM / 2), wn = (w >> 1) * 64;
  const bf16* Bp = (bm < half) ? B0 : B1;
  const float* bias = (bm < half) ? bias0 : bias1;

  f32x4 acc[MI][4];
#pragma unroll
  for (int mi = 0; mi < MI; ++mi)
#pragma unroll
    for (int ni = 0; ni < 4; ++ni) acc[mi][ni] = (f32x4){0.f, 0.f, 0.f, 0.f};

  for (int k0 = 0; k0 < K; k0 += 64) {
    __syncthreads();
#pragma unroll
    for (int it = 0; it < BM / 32; ++it) {
      int lc = it * 256 + tid;
      int m = lc >> 3, k8 = lc & 7;
      uint4 v = *(const uint4*)((const char*)A + ((long)(bm + m) * K + k0 + k8 * 8) * 2);
      *(uint4*)&As[(m * 8 + (k8 ^ (m & 7))) * 8] = v;
    }
#pragma unroll
    for (int it = 0; it < 4; ++it) {
      int lc = it * 256 + tid;
      int n = lc >> 3, k8 = lc & 7;
      uint4 v = *(const uint4*)((const char*)Bp + ((long)(bn + n) * K + k0 + k8 * 8) * 2);
      *(uint4*)&Bs[(n * 8 + (k8 ^ (n & 7))) * 8] = v;
    }
    __syncthreads();
#pragma unroll
    for (int ks = 0; ks < 2; ++ks) {
      short8 af[MI], bfr[4];
#pragma unroll
      for (int mi = 0; mi < MI; ++mi) {
        int row = wm + mi * 16 + lm;
        af[mi] = *(const short8*)&As[row * 64 + ((ks * 4 + q) ^ (lm & 7)) * 8];
      }
#pragma unroll
      for (int ni = 0; ni < 4; ++ni) {
        int row = wn + ni * 16 + lm;
        bfr[ni] = *(const short8*)&Bs[row * 64 + ((ks * 4 + q) ^ (lm & 7)) * 8];
      }
#pragma unroll
      for (int mi = 0; mi < MI; ++mi)
#pragma unroll
        for (int ni = 0; ni < 4; ++ni)
          acc[mi][ni] = __builtin_amdgcn_mfma_f32_16x16x32_bf16(af[mi], bfr[ni], acc[mi][ni], 0, 0, 0);
    }
  }
#pragma unroll
  for (int mi = 0; mi < MI; ++mi) {
#pragma unroll
    for (int ni = 0; ni < 4; ++ni) {
      int col = bn + wn + ni * 16 + lm;
      float bcol = bias[col];
#pragma unroll
      for (int r = 0; r < 4; ++r) {
        int row = bm + wm + mi * 16 + q * 4 + r;
        float v = acc[mi][ni][r] + bcol;
        if (SILU) v = siluf(v);
        if (XE) v *= xe[(row / 3) * HH + col];
        if (OUT_BF16) ((bf16*)Cout)[(long)row * N + col] = f2b(v);
        else ((float*)Cout)[(long)row * N + col] = v;
      }
    }
  }
}

// ---------------- osum = silu(h1 @ Wn1b + b1) + silu(h2 @ Wn2b + b2): M=4096, N=2048, K=128 ----------------
__global__ __launch_bounds__(256) void gemm_osum(
    const bf16* __restrict__ A, const bf16* __restrict__ B0w, const bf16* __restrict__ B1w,
    const float* __restrict__ bias0, const float* __restrict__ bias1,
    float* __restrict__ osum) {
  __shared__ short As[128 * 64];
  __shared__ short Bs[128 * 64];
  const int tid = threadIdx.x;
  const int w = tid >> 6, lane = tid & 63;
  const int lm = lane & 15, q = lane >> 4;
  const int bm = blockIdx.x * 128, bn = blockIdx.y * 128;
  const int wm = (w & 1) * 64, wn = (w >> 1) * 64;
  f32x4 ov[4][4];
  f32x4 acc[4][4];
#pragma unroll
  for (int mi = 0; mi < 4; ++mi)
#pragma unroll
    for (int ni = 0; ni < 4; ++ni) acc[mi][ni] = (f32x4){0.f, 0.f, 0.f, 0.f};

#pragma unroll 1
  for (int src = 0; src < 2; ++src) {
    const bf16* Ap = A + (long)src * 4096 * 128;
    const bf16* Bp = src ? B1w : B0w;
#pragma unroll 1
    for (int k0 = 0; k0 < 128; k0 += 64) {
      __syncthreads();
#pragma unroll
      for (int it = 0; it < 4; ++it) {
        int lc = it * 256 + tid;
        int m = lc >> 3, k8 = lc & 7;
        uint4 v = *(const uint4*)((const char*)Ap + ((long)(bm + m) * 128 + k0 + k8 * 8) * 2);
        *(uint4*)&As[(m * 8 + (k8 ^ (m & 7))) * 8] = v;
      }
#pragma unroll
      for (int it = 0; it < 4; ++it) {
        int lc = it * 256 + tid;
        int n = lc >> 3, k8 = lc & 7;
        uint4 v = *(const uint4*)((const char*)Bp + ((long)(bn + n) * 128 + k0 + k8 * 8) * 2);
        *(uint4*)&Bs[(n * 8 + (k8 ^ (n & 7))) * 8] = v;
      }
      __syncthreads();
#pragma unroll
      for (int ks = 0; ks < 2; ++ks) {
        short8 af[4], bfr[4];
#pragma unroll
        for (int mi = 0; mi < 4; ++mi)
          af[mi] = *(const short8*)&As[(wm + mi * 16 + lm) * 64 + ((ks * 4 + q) ^ (lm & 7)) * 8];
#pragma unroll
        for (int ni = 0; ni < 4; ++ni)
          bfr[ni] = *(const short8*)&Bs[(wn + ni * 16 + lm) * 64 + ((ks * 4 + q) ^ (lm & 7)) * 8];
#pragma unroll
        for (int mi = 0; mi < 4; ++mi)
#pragma unroll
          for (int ni = 0; ni < 4; ++ni)
            acc[mi][ni] = __builtin_amdgcn_mfma_f32_16x16x32_bf16(af[mi], bfr[ni], acc[mi][ni], 0, 0, 0);
      }
    }
    if (src == 0) {
#pragma unroll
      for (int mi = 0; mi < 4; ++mi)
#pragma unroll
        for (int ni = 0; ni < 4; ++ni) {
          int col = bn + wn + ni * 16 + lm;
          float bc = bias0[col];
#pragma unroll
          for (int r = 0; r < 4; ++r) ov[mi][ni][r] = siluf(acc[mi][ni][r] + bc);
#pragma unroll
          for (int r = 0; r < 4; ++r) acc[mi][ni][r] = 0.f;
        }
    }
  }
#pragma unroll
  for (int mi = 0; mi < 4; ++mi)
#pragma unroll
    for (int ni = 0; ni < 4; ++ni) {
      int col = bn + wn + ni * 16 + lm;
      float bc = bias1[col];
#pragma unroll
      for (int r = 0; r < 4; ++r) {
        int row = bm + wm + mi * 16 + q * 4 + r;
        osum[(long)row * 2048 + col] = ov[mi][ni][r] + siluf(acc[mi][ni][r] + bc);
      }
    }
}

// ---------------- fused: sh = wig_node @ osum; z = 2(xs+xt)+asum+pad(sh); msg = wigner @ z ------------
// 512 threads / edge. Split-bf16 (hi/lo, 3 products) keeps fp32-equivalent accuracy.
__global__ __launch_bounds__(512, 4) void rotate_msg_fused_kernel(
    const float* __restrict__ x, const float* __restrict__ wigner,
    const int* __restrict__ eidx, const float* __restrict__ asum,
    const float* __restrict__ osum, const float* __restrict__ wig_node,
    bf16* __restrict__ msg) {
  __shared__ bf16 Ah[48 * 64], Al[48 * 64];        // wigner hi/lo, XOR-swizzled rows (12 KB)
  __shared__ bf16 zTh[128 * 64], zTl[128 * 64];    // z^T hi/lo, GEMM-B layout (32 KB)
  __shared__ float z[49 * 132];                    // fp32 z (25.9 KB)
  __shared__ float osum_s[16 * 128];               // wig_node-rotated input (8 KB)
  __shared__ float wig[256];
  __shared__ float as_s[49];
  const int e = blockIdx.x, tid = threadIdx.x;
  const int s = eidx[e], d = eidx[EE + e];
  const int w = tid >> 6, lane = tid & 63;
  const int lm = lane & 15, q = lane >> 4;

  // ---- P1: stage everything (independent vector loads) ----
  if (tid < 49) as_s[tid] = asum[e * 64 + tid];
  if (tid >= 64 && tid < 128) {
    int i = tid - 64;
    *(float4*)&wig[i * 4] = *(const float4*)&wig_node[(long)e * 256 + i * 4];
  }
  *(float4*)&osum_s[tid * 4] = *(const float4*)&osum[(long)e * 2048 + tid * 4];
  for (int i = tid; i < 48 * 15; i += 512) {  // A zero-pad k in [49,64)
    int m = i / 15, k = 49 + (i - m * 15);
    int off = m * 64 + (((k >> 3) ^ (m & 7)) << 3) + (k & 7);
    Ah[off] = f2b(0.f); Al[off] = f2b(0.f);
  }
  for (int i4 = tid; i4 < 588; i4 += 512) {   // wigner -> Ah/Al (float4 loads)
    float4 v4 = *(const float4*)&wigner[(long)e * 2352 + i4 * 4];
    int i = i4 * 4;
    int m = i / 49, k = i - m * 49;
    float vv[4] = {v4.x, v4.y, v4.z, v4.w};
#pragma unroll
    for (int j = 0; j < 4; ++j) {
      bf16 h = f2b(vv[j]);
      bf16 l = f2b(vv[j] - __bfloat162float(h));
      int off = m * 64 + (((k >> 3) ^ (m & 7)) << 3) + (k & 7);
      Ah[off] = h; Al[off] = l;
      if (++k == 49) { k = 0; ++m; }
    }
  }
  __syncthreads();

  // ---- P2: z build (float4 writes, conflict-free), sh fused inline for rows l<16 ----
  {
    const float* xs = x + (long)s * (LL * CC);
    const float* xt = x + (long)d * (LL * CC);
    for (int i4 = tid; i4 < 49 * 32; i4 += 512) {
      int l = i4 >> 5, c4 = i4 & 31;
      float4 a = *(const float4*)&xs[l * 128 + c4 * 4];
      float4 b = *(const float4*)&xt[l * 128 + c4 * 4];
      float ad = as_s[l];
      float4 v;
      v.x = 2.f * (a.x + b.x) + ad;
      v.y = 2.f * (a.y + b.y) + ad;
      v.z = 2.f * (a.z + b.z) + ad;
      v.w = 2.f * (a.w + b.w) + ad;
      if (l < 16) {
#pragma unroll
        for (int j = 0; j < 16; ++j) {
          float wv = wig[l * 16 + j];                       // broadcast
          float4 o = *(const float4*)&osum_s[j * 128 + c4 * 4];
          v.x += wv * o.x; v.y += wv * o.y; v.z += wv * o.z; v.w += wv * o.w;
        }
      }
      *(float4*)&z[l * 132 + c4 * 4] = v;
    }
  }
  __syncthreads();

  // ---- P3: transpose via 4x float4 reads (conflict-free granule map) + 8B packed writes (2-way) ----
  {
    const int b0 = (tid & 15) * 4;
    const int c0 = (tid >> 4) * 4;
    float4 rv[4];
#pragma unroll
    for (int j = 0; j < 4; ++j)
      rv[j] = (b0 + j < 49) ? *(const float4*)&z[(b0 + j) * 132 + c0]
                            : (float4){0.f, 0.f, 0.f, 0.f};
#pragma unroll
    for (int i = 0; i < 4; ++i) {
      int c = c0 + i;
      union { bf16 b[4]; unsigned long long u; } hu, lu;
#pragma unroll
      for (int j = 0; j < 4; ++j) {
        float v = getc(rv[j], i);
        bf16 h = f2b(v);
        hu.b[j] = h;
        lu.b[j] = f2b(v - __bfloat162float(h));
      }
      int off = c * 64 + (((b0 >> 3) ^ (c & 7)) << 3) + (b0 & 7);
      *(unsigned long long*)&zTh[off] = hu.u;
      *(unsigned long long*)&zTl[off] = lu.u;
    }
  }
  __syncthreads();

  // ---- P4: MFMA (wave w -> n-tile w, m-tiles = NY taps) + store ----
  short8 ah[3][2], alo[3][2], bh[2], bl[2];
#pragma unroll
  for (int mi = 0; mi < 3; ++mi)
#pragma unroll
    for (int ks = 0; ks < 2; ++ks) {
      int off = (mi * 16 + lm) * 64 + (((ks * 4 + q) ^ (lm & 7)) << 3);
      ah[mi][ks] = *(const short8*)&Ah[off];
      alo[mi][ks] = *(const short8*)&Al[off];
    }
#pragma unroll
  for (int ks = 0; ks < 2; ++ks) {
    int off = (w * 16 + lm) * 64 + (((ks * 4 + q) ^ (lm & 7)) << 3);
    bh[ks] = *(const short8*)&zTh[off];
    bl[ks] = *(const short8*)&zTl[off];
  }
  f32x4 acc[3];
#pragma unroll
  for (int mi = 0; mi < 3; ++mi) acc[mi] = (f32x4){0.f, 0.f, 0.f, 0.f};
#pragma unroll
  for (int mi = 0; mi < 3; ++mi)
#pragma unroll
    for (int ks = 0; ks < 2; ++ks) {
      acc[mi] = __builtin_amdgcn_mfma_f32_16x16x32_bf16(ah[mi][ks], bh[ks], acc[mi], 0, 0, 0);
      acc[mi] = __builtin_amdgcn_mfma_f32_16x16x32_bf16(ah[mi][ks], bl[ks], acc[mi], 0, 0, 0);
      acc[mi] = __builtin_amdgcn_mfma_f32_16x16x32_bf16(alo[mi][ks], bh[ks], acc[mi], 0, 0, 0);
    }
  {
    int c = w * 16 + lm;
#pragma unroll
    for (int mi = 0; mi < 3; ++mi) {
      long base = ((long)e * 3 + mi) * 2048 + c;
#pragma unroll
      for (int r = 0; r < 4; ++r)
        msg[base + (q * 4 + r) * 128] = f2b(acc[mi][r]);
    }
  }
}

// ---------------- fused m2 GEMM + CombineYRotations + RotateInv: 4 edges / block ----------------
// m2 = silu(m1 @ Wp2 + bp2) [12 rows x 2048]; mr = mean3; out = inv_sqrt3 * wigner_inv @ mr
__global__ __launch_bounds__(512) void m2out_kernel(
    const bf16* __restrict__ m1, const bf16* __restrict__ BTp2,
    const float* __restrict__ bp2, const float* __restrict__ wigner_inv,
    float* __restrict__ out) {
  __shared__ __align__(16) char sm[4096 + 32768 + 8448 + 32768];
  short (*As)[1024] = (short(*)[1024])sm;                  // [2][16*64]
  short (*Bs)[8192] = (short(*)[8192])(sm + 4096);         // [2][128*64]
  float* pbuf = (float*)(sm + 4096 + 32768);               // [16*132]
  float* mr   = (float*)(sm + 4096 + 32768 + 8448);        // [4*2048]
  float* wv_s = (float*)(sm + 4096);                       // alias of Bs (used after chunk loop)

  const int tid = threadIdx.x;
  const int w = tid >> 6, lane = tid & 63;
  const int lm = lane & 15, q = lane >> 4;
  const int e0 = blockIdx.x * 4;

  // stage A: 12 real rows of m1 -> 16 padded, swizzled per 64-k half
  if (tid < 256) {
    int n = tid >> 4, k8 = tid & 15;
    uint4 v = (uint4){0, 0, 0, 0};
    if (n < 12) v = *(const uint4*)((const char*)m1 + ((long)(e0 * 3 + n) * 128 + k8 * 8) * 2);
    *(uint4*)&As[k8 >> 3][(n * 8 + ((k8 & 7) ^ (n & 7))) * 8] = v;
  }

#pragma unroll 1
  for (int nc = 0; nc < 16; ++nc) {
    __syncthreads();
#pragma unroll
    for (int it = 0; it < 4; ++it) {
      int lc = it * 512 + tid;
      int n = lc >> 4, k8 = lc & 15;
      uint4 v = *(const uint4*)((const char*)BTp2 + ((long)(nc * 128 + n) * 128 + k8 * 8) * 2);
      *(uint4*)&Bs[k8 >> 3][(n * 8 + ((k8 & 7) ^ (n & 7))) * 8] = v;
    }
    __syncthreads();
    f32x4 acc = (f32x4){0.f, 0.f, 0.f, 0.f};
#pragma unroll
    for (int ks = 0; ks < 4; ++ks) {
      int kh = ks >> 1, ksl = ks & 1;
      short8 af = *(const short8*)&As[kh][(lm * 8 + ((ksl * 4 + q) ^ (lm & 7))) * 8];
      int brow = w * 16 + lm;
      short8 bfr = *(const short8*)&Bs[kh][(brow * 8 + ((ksl * 4 + q) ^ (brow & 7))) * 8];
      acc = __builtin_amdgcn_mfma_f32_16x16x32_bf16(af, bfr, acc, 0, 0, 0);
    }
    {
      int col = w * 16 + lm;
      float bc = bp2[nc * 128 + col];
#pragma unroll
      for (int r = 0; r < 4; ++r)
        pbuf[(q * 4 + r) * 132 + col] = siluf(acc[r] + bc);
    }
    __syncthreads();
    {
      int c = tid & 127, e4 = tid >> 7;
      mr[e4 * 2048 + nc * 128 + c] =
          (pbuf[(3 * e4 + 0) * 132 + c] + pbuf[(3 * e4 + 1) * 132 + c] +
           pbuf[(3 * e4 + 2) * 132 + c]) * (1.f / 3.f);
    }
  }
  __syncthreads();
  // stage wigner_inv for 4 edges (3136 floats, aliases Bs)
  for (int i4 = tid; i4 < 784; i4 += 512)
    *(float4*)&wv_s[i4 * 4] = *(const float4*)&wigner_inv[(long)e0 * 784 + i4 * 4];
  __syncthreads();
  // rotation: out[e][b][c] = inv_sqrt3 * sum_r wv[e][b*16+r] * mr[e][r*128+c]
  {
    const int c4 = tid & 31, sb = (tid >> 5) & 3, ep = tid >> 7;
#pragma unroll 1
    for (int bb = 0; bb < 13; ++bb) {
      int b = bb * 4 + sb;
      if (b < 49) {
        float a0 = 0.f, a1 = 0.f, a2 = 0.f, a3 = 0.f;
#pragma unroll
        for (int r = 0; r < 16; ++r) {
          float wvv = wv_s[ep * 784 + b * 16 + r];
          const float4 m = *(const float4*)&mr[ep * 2048 + r * 128 + c4 * 4];
          a0 += wvv * m.x; a1 += wvv * m.y; a2 += wvv * m.z; a3 += wvv * m.w;
        }
        float4 o;
        o.x = a0 * 0.57735026918962576f; o.y = a1 * 0.57735026918962576f;
        o.z = a2 * 0.57735026918962576f; o.w = a3 * 0.57735026918962576f;
        *(float4*)&out[(long)(e0 + ep) * 6272 + b * 128 + c4 * 4] = o;
      }
    }
  }
}

// ---------------- host side ----------------
extern "C" void kernel_launch(void* const* d_in, const int* in_sizes, int n_in,
                              void* d_out, int out_size, void* d_ws, size_t ws_size,
                              hipStream_t stream) {
  (void)in_sizes; (void)n_in; (void)out_size; (void)ws_size;
  const float* x        = (const float*)d_in[0];
  const float* x_glovec = (const float*)d_in[2];
  const float* x_edge   = (const float*)d_in[3];
  const int*   eidx     = (const int*)d_in[4];
  const float* W_cg1   = (const float*)d_in[8];
  const float* W_cg21  = (const float*)d_in[9];
  const float* W_cg22  = (const float*)d_in[10];
  const float* Wn1a = (const float*)d_in[11];
  const float* bn1a = (const float*)d_in[12];
  const float* Wn1b = (const float*)d_in[13];
  const float* bn1b = (const float*)d_in[14];
  const float* Wn2a = (const float*)d_in[15];
  const float* bn2a = (const float*)d_in[16];
  const float* Wn2b = (const float*)d_in[17];
  const float* bn2b = (const float*)d_in[18];
  const float* Wd   = (const float*)d_in[19];
  const float* bd   = (const float*)d_in[20];
  const float* Wp1  = (const float*)d_in[21];
  const float* bp1  = (const float*)d_in[22];
  const float* Wp2  = (const float*)d_in[23];
  const float* bp2  = (const float*)d_in[24];
  const float* wigner     = (const float*)d_in[25];
  const float* wigner_inv = (const float*)d_in[26];
  const float* wig_node   = (const float*)d_in[27];

  char* W = (char*)d_ws;
  bf16*  featst = (bf16*)(W + 0);            // 8192 x 2112 bf16 (34.6 MB)
  float* p_osum = (float*)(W + 34603008);    // 4096 x 2048 f32 (33.5 MB)
  bf16*  msg    = (bf16*)(W + 135266304);    // 12288 x 2048 bf16 (50.3 MB)
  bf16*  P1     = (bf16*)(W + 135266304);    // alias in msg region: 4096 x 2432 bf16 (19.9 MB)
  bf16*  P2     = (bf16*)(W + 155189248);    // alias in msg region: 4096 x 2496 bf16 (20.4 MB)
  bf16*  hstack = (bf16*)(W + 185597952);    // 8192 x 128 bf16
  bf16*  m1     = (bf16*)(W + 187695104);    // 12288 x 128 bf16
  float* p_xe   = (float*)(W + 190840832);   // 4096 x 128 f32
  float* p_xmean= (float*)(W + 192937984);   // 100352 f32
  bf16*  BTa    = (bf16*)(W + 194142208);    // 2 x 128 x 2112
  bf16*  BTb    = (bf16*)(W + 195223552);    // 2 x 2048 x 128
  bf16*  BTp1   = (bf16*)(W + 196272128);    // 128 x 2048
  bf16*  BTp2   = (bf16*)(W + 196796416);    // 2048 x 128 (ends 197320704)
  float* p_asum = (float*)(W + 197320704);   // 4096 x 64 f32 (1 MB)
  float* p_mid  = (float*)(W + 198369280);   // 4096 x 32 f32 (512 KB)
  bf16*  BT1    = (bf16*)(W + 198893568);    // 32 x 2432 bf16 (152 KB)
  bf16*  BT2    = (bf16*)(W + 199049216);    // 64 x 2496 bf16 (312 KB; ends 199368704)

  TJobs tj;
  tj.j[0] = {Wn1a, BTa,            2064, 128, 2112};
  tj.j[1] = {Wn2a, BTa + 270336,   2064, 128, 2112};
  tj.j[2] = {Wn1b, BTb,            128, 2048, 128};
  tj.j[3] = {Wn2b, BTb + 262144,   128, 2048, 128};
  tj.j[4] = {Wp1,  BTp1,           2048, 128, 2048};
  tj.j[5] = {Wp2,  BTp2,           128, 2048, 128};
  transpose_cvt_kernel<<<dim3(1056, 6), 256, 0, stream>>>(tj);
  cg_prep_kernel<<<dim3(624, 2), 256, 0, stream>>>(W_cg1, W_cg21, W_cg22, BT1, BT2);

  node_mean_kernel<<<(NN * LL) / 4, 256, 0, stream>>>(x, p_xmean);
  // CG bilinears as outer-product GEMMs
  build_p1_kernel<<<EE, 256, 0, stream>>>(p_xmean, eidx, P1);
  gemm_smalln<2><<<EE / 64, 256, 0, stream>>>(P1, BT1, p_mid, K1P);
  build_p2_kernel<<<EE, 256, 0, stream>>>(p_xmean, p_mid, eidx, P2);
  gemm_smalln<4><<<EE / 64, 256, 0, stream>>>(P2, BT2, p_asum, K2P);

  gemm_f32_silu<<<dim3(EE / 64, 2), 256, 0, stream>>>(x_edge, Wd, bd, p_xe, EE, HH, 128);
  build_feat_kernel<<<EE, 256, 0, stream>>>(x, x_glovec, wig_node, eidx, featst);
  // h = silu(feat @ Wna): M=8192, N=128, K=2112, stacked weights
  gemm_mfma<64, true, false, true><<<dim3(128, 1), 256, 0, stream>>>(
      featst, BTa, BTa + 270336, bn1a, bn2a, nullptr, hstack, 8192, 128, 2112, 4096);
  // osum = silu(h1 @ Wn1b + b1) + silu(h2 @ Wn2b + b2): M=4096, N=2048, K=128
  gemm_osum<<<dim3(32, 16), 256, 0, stream>>>(hstack, BTb, BTb + 262144, bn1b, bn2b, p_osum);
  // fused rotback + z-build + msg GEMM
  rotate_msg_fused_kernel<<<EE, 512, 0, stream>>>(
      x, wigner, eidx, p_asum, p_osum, wig_node, msg);
  // m1 = silu(msg @ Wp1) * xe: M=12288, N=128, K=2048, bf16 out
  gemm_mfma<64, true, true, true><<<dim3(192, 1), 256, 0, stream>>>(
      msg, BTp1, BTp1, bp1, bp1, p_xe, m1, 12288, 128, 2048, 1 << 30);
  // fused m2 GEMM + mean_ny + RotateInv -> out
  m2out_kernel<<<EE / 4, 512, 0, stream>>>(m1, BTp2, bp2, wigner_inv, (float*)d_out);
}